// Round 1
// baseline (2489.388 us; speedup 1.0000x reference)
//
#include <hip/hip_runtime.h>

#define ND 50000
#define NS 30000
#define NE 1000000
#define EL 200000
#define HD 256           // hidden / feature dim
#define CHUNK 50000      // decoder chunk (EL = 4 * CHUNK exactly)

// ---------------- utility kernels ----------------

__global__ void zero2_kernel(int* a, int na, int* b, int nb) {
    int i = blockIdx.x * blockDim.x + threadIdx.x;
    if (i < na) a[i] = 0;
    if (i < nb) b[i] = 0;
}

__global__ void hist_kernel(const int* __restrict__ src, const int* __restrict__ dst,
                            int* cnt_drug, int* cnt_dis, int n) {
    int i = blockIdx.x * blockDim.x + threadIdx.x;
    if (i < n) {
        atomicAdd(&cnt_dis[dst[i]], 1);
        atomicAdd(&cnt_drug[src[i]], 1);
    }
}

// single-block exclusive scan; also emits cursor copy and 1/max(cnt,1)
__global__ void scan_kernel(const int* __restrict__ cnt, int* __restrict__ row_ptr,
                            int* __restrict__ cursor, float* __restrict__ inv, int n) {
    __shared__ int sums[256];
    __shared__ int base_sh[256];
    int t = threadIdx.x;
    int chunk = (n + 255) / 256;
    int s0 = t * chunk;
    int s1 = s0 + chunk; if (s1 > n) s1 = n; if (s0 > n) s0 = n;
    int lsum = 0;
    for (int i = s0; i < s1; ++i) lsum += cnt[i];
    sums[t] = lsum;
    __syncthreads();
    if (t == 0) {
        int run = 0;
        for (int i = 0; i < 256; ++i) { base_sh[i] = run; run += sums[i]; }
    }
    __syncthreads();
    int run = base_sh[t];
    for (int i = s0; i < s1; ++i) {
        int c = cnt[i];
        row_ptr[i] = run;
        cursor[i] = run;
        inv[i] = 1.0f / (float)(c > 1 ? c : 1);
        run += c;
    }
    if (t == 255) row_ptr[n] = run;
}

__global__ void scatter_kernel(const int* __restrict__ src, const int* __restrict__ dst,
                               int* cur_drug, int* cur_dis,
                               int* __restrict__ val_sd, int* __restrict__ val_ds, int n) {
    int i = blockIdx.x * blockDim.x + threadIdx.x;
    if (i < n) {
        int s = src[i], d = dst[i];
        int p = atomicAdd(&cur_dis[d], 1);
        val_ds[p] = s;                       // neighbors (drug ids) of each disease
        int q = atomicAdd(&cur_drug[s], 1);
        val_sd[q] = d;                       // neighbors (disease ids) of each drug
    }
}

// one wave per destination node: accumulate neighbor rows, write mean
__global__ __launch_bounds__(256) void agg_kernel(const float* __restrict__ xsrc,
                                                  const int* __restrict__ row_ptr,
                                                  const int* __restrict__ vals,
                                                  const float* __restrict__ inv,
                                                  float* __restrict__ outp, int n_dst) {
    int wid = threadIdx.x >> 6;
    int lane = threadIdx.x & 63;
    int node = blockIdx.x * 4 + wid;
    if (node >= n_dst) return;
    int beg = row_ptr[node], end = row_ptr[node + 1];
    int off = lane * 4;
    float4 acc = make_float4(0.f, 0.f, 0.f, 0.f);
    for (int j = beg; j < end; ++j) {
        int s = vals[j];
        const float4 v = *reinterpret_cast<const float4*>(xsrc + (size_t)s * HD + off);
        acc.x += v.x; acc.y += v.y; acc.z += v.z; acc.w += v.w;
    }
    float iv = inv[node];
    acc.x *= iv; acc.y *= iv; acc.z *= iv; acc.w *= iv;
    *reinterpret_cast<float4*>(outp + (size_t)node * HD + off) = acc;
}

// C[M,256] = act(A1[g1,256]@B1[256,256] + A2[g2,256]@B2[256,256] + bias)
// idx1/idx2 optionally gather A rows. 64x64 tile, BK=16, 256 threads, 4x4 microtile.
__global__ __launch_bounds__(256) void gemm_fused(const float* __restrict__ A1,
                                                  const float* __restrict__ A2,
                                                  const int* __restrict__ idx1,
                                                  const int* __restrict__ idx2,
                                                  const float* __restrict__ B1,
                                                  const float* __restrict__ B2,
                                                  const float* __restrict__ bias,
                                                  float* __restrict__ C,
                                                  int M, int do_relu) {
    __shared__ float As[16][64];
    __shared__ float Bs[16][64];
    const int t = threadIdx.x;
    const int bx = blockIdx.x;
    const int n0 = blockIdx.y * 64;
    const int ty = t >> 4, tx = t & 15;
    const int lm = t >> 2, lk4 = (t & 3) * 4;      // A-load: row lm, k offset lk4
    const int lkb = t >> 4, ln4 = (t & 15) * 4;    // B-load: k row lkb, col ln4

    int arow = bx * 64 + lm;
    if (arow >= M) arow = M - 1;
    const int a1row = idx1 ? idx1[arow] : arow;
    const int a2row = idx2 ? idx2[arow] : arow;

    float acc[4][4] = {};

    for (int kt = 0; kt < 32; ++kt) {
        int k0 = kt * 16;
        const float* Ap;
        const float* Bp;
        int ka;
        if (k0 < 256) { Ap = A1 + (size_t)a1row * HD; Bp = B1; ka = k0; }
        else          { Ap = A2 + (size_t)a2row * HD; Bp = B2; ka = k0 - 256; }

        const float4 av = *reinterpret_cast<const float4*>(Ap + ka + lk4);
        const float4 bv = *reinterpret_cast<const float4*>(Bp + (size_t)(ka + lkb) * HD + n0 + ln4);

        __syncthreads();
        As[lk4 + 0][lm] = av.x;
        As[lk4 + 1][lm] = av.y;
        As[lk4 + 2][lm] = av.z;
        As[lk4 + 3][lm] = av.w;
        *reinterpret_cast<float4*>(&Bs[lkb][ln4]) = bv;
        __syncthreads();

#pragma unroll
        for (int kk = 0; kk < 16; ++kk) {
            const float4 a4 = *reinterpret_cast<const float4*>(&As[kk][ty * 4]);
            const float4 b4 = *reinterpret_cast<const float4*>(&Bs[kk][tx * 4]);
            const float a_[4] = { a4.x, a4.y, a4.z, a4.w };
            const float b_[4] = { b4.x, b4.y, b4.z, b4.w };
#pragma unroll
            for (int i = 0; i < 4; ++i)
#pragma unroll
                for (int j = 0; j < 4; ++j)
                    acc[i][j] = fmaf(a_[i], b_[j], acc[i][j]);
        }
    }

    const int crow = bx * 64 + ty * 4;
    const int ccol = n0 + tx * 4;
#pragma unroll
    for (int i = 0; i < 4; ++i) {
        int r = crow + i;
        if (r >= M) break;
        float4 v;
        v.x = acc[i][0] + bias[ccol + 0];
        v.y = acc[i][1] + bias[ccol + 1];
        v.z = acc[i][2] + bias[ccol + 2];
        v.w = acc[i][3] + bias[ccol + 3];
        if (do_relu) {
            v.x = fmaxf(v.x, 0.f); v.y = fmaxf(v.y, 0.f);
            v.z = fmaxf(v.z, 0.f); v.w = fmaxf(v.w, 0.f);
        }
        *reinterpret_cast<float4*>(C + (size_t)r * HD + ccol) = v;
    }
}

// out[e] = dot(h[e,:], W2) + b2  -- one wave per edge
__global__ __launch_bounds__(256) void dec2_kernel(const float* __restrict__ h,
                                                   const float* __restrict__ W2,
                                                   const float* __restrict__ b2,
                                                   float* __restrict__ outp, int n) {
    int wid = threadIdx.x >> 6;
    int lane = threadIdx.x & 63;
    int e = blockIdx.x * 4 + wid;
    if (e >= n) return;
    const float4 hv = *reinterpret_cast<const float4*>(h + (size_t)e * HD + lane * 4);
    const float4 wv = *reinterpret_cast<const float4*>(W2 + lane * 4);
    float s = hv.x * wv.x + hv.y * wv.y + hv.z * wv.z + hv.w * wv.w;
#pragma unroll
    for (int off = 32; off; off >>= 1) s += __shfl_down(s, off);
    if (lane == 0) outp[e] = s + b2[0];
}

// ---------------- launch ----------------

extern "C" void kernel_launch(void* const* d_in, const int* in_sizes, int n_in,
                              void* d_out, int out_size, void* d_ws, size_t ws_size,
                              hipStream_t stream) {
    const float* x_drug = (const float*)d_in[0];
    const float* x_dis  = (const float*)d_in[1];
    const int* esrc = (const int*)d_in[2];
    const int* edst = (const int*)d_in[3];
    const int* lrow = (const int*)d_in[4];
    const int* lcol = (const int*)d_in[5];
    const float* Wl1_ds = (const float*)d_in[6];
    const float* bl1_ds = (const float*)d_in[7];
    const float* Wr1_ds = (const float*)d_in[8];
    const float* Wl1_sd = (const float*)d_in[9];
    const float* bl1_sd = (const float*)d_in[10];
    const float* Wr1_sd = (const float*)d_in[11];
    const float* Wl2_ds = (const float*)d_in[12];
    const float* bl2_ds = (const float*)d_in[13];
    const float* Wr2_ds = (const float*)d_in[14];
    const float* Wl2_sd = (const float*)d_in[15];
    const float* bl2_sd = (const float*)d_in[16];
    const float* Wr2_sd = (const float*)d_in[17];
    const float* Wdec1 = (const float*)d_in[18];
    const float* bdec1 = (const float*)d_in[19];
    const float* Wdec2 = (const float*)d_in[20];
    const float* bdec2 = (const float*)d_in[21];
    float* outp = (float*)d_out;

    char* ws = (char*)d_ws;
    size_t off = 0;
    auto alloc = [&](size_t bytes) -> void* {
        void* p = ws + off;
        off = (off + bytes + 255) & ~(size_t)255;
        return p;
    };
    int* cnt_dis   = (int*)alloc((size_t)NS * 4);
    int* cnt_drug  = (int*)alloc((size_t)ND * 4);
    int* row_dis   = (int*)alloc((size_t)(NS + 1) * 4);
    int* row_drug  = (int*)alloc((size_t)(ND + 1) * 4);
    int* cur_dis   = (int*)alloc((size_t)NS * 4);
    int* cur_drug  = (int*)alloc((size_t)ND * 4);
    float* inv_dis = (float*)alloc((size_t)NS * 4);
    float* inv_drug= (float*)alloc((size_t)ND * 4);
    int* val_ds    = (int*)alloc((size_t)NE * 4);
    int* val_sd    = (int*)alloc((size_t)NE * 4);
    float* agg     = (float*)alloc((size_t)ND * HD * 4);  // also reused as decoder h
    float* zd1     = (float*)alloc((size_t)ND * HD * 4);
    float* zs1     = (float*)alloc((size_t)NS * HD * 4);
    float* zd2     = (float*)alloc((size_t)ND * HD * 4);
    float* zs2     = (float*)alloc((size_t)NS * HD * 4);

    // --- build CSR (both directions) ---
    {
        int mx = ND > NS ? ND : NS;
        zero2_kernel<<<(mx + 255) / 256, 256, 0, stream>>>(cnt_dis, NS, cnt_drug, ND);
        hist_kernel<<<(NE + 255) / 256, 256, 0, stream>>>(esrc, edst, cnt_drug, cnt_dis, NE);
        scan_kernel<<<1, 256, 0, stream>>>(cnt_dis, row_dis, cur_dis, inv_dis, NS);
        scan_kernel<<<1, 256, 0, stream>>>(cnt_drug, row_drug, cur_drug, inv_drug, ND);
        scatter_kernel<<<(NE + 255) / 256, 256, 0, stream>>>(esrc, edst, cur_drug, cur_dis,
                                                             val_sd, val_ds, NE);
    }

    dim3 gemm_grid_ns((NS + 63) / 64, 4);
    dim3 gemm_grid_nd((ND + 63) / 64, 4);

    // --- layer 1 ---
    agg_kernel<<<(NS + 3) / 4, 256, 0, stream>>>(x_drug, row_dis, val_ds, inv_dis, agg, NS);
    gemm_fused<<<gemm_grid_ns, 256, 0, stream>>>(agg, x_dis, nullptr, nullptr,
                                                 Wl1_ds, Wr1_ds, bl1_ds, zs1, NS, 1);
    agg_kernel<<<(ND + 3) / 4, 256, 0, stream>>>(x_dis, row_drug, val_sd, inv_drug, agg, ND);
    gemm_fused<<<gemm_grid_nd, 256, 0, stream>>>(agg, x_drug, nullptr, nullptr,
                                                 Wl1_sd, Wr1_sd, bl1_sd, zd1, ND, 1);

    // --- layer 2 (no relu) ---
    agg_kernel<<<(NS + 3) / 4, 256, 0, stream>>>(zd1, row_dis, val_ds, inv_dis, agg, NS);
    gemm_fused<<<gemm_grid_ns, 256, 0, stream>>>(agg, zs1, nullptr, nullptr,
                                                 Wl2_ds, Wr2_ds, bl2_ds, zs2, NS, 0);
    agg_kernel<<<(ND + 3) / 4, 256, 0, stream>>>(zs1, row_drug, val_sd, inv_drug, agg, ND);
    gemm_fused<<<gemm_grid_nd, 256, 0, stream>>>(agg, zd1, nullptr, nullptr,
                                                 Wl2_sd, Wr2_sd, bl2_sd, zd2, ND, 0);

    // --- decoder, chunked; h reuses agg buffer ---
    float* hbuf = agg;
    const float* Wd1_top = Wdec1;              // rows 0..255   (zd part)
    const float* Wd1_bot = Wdec1 + 256 * HD;   // rows 256..511 (zs part)
    for (int c0 = 0; c0 < EL; c0 += CHUNK) {
        int n = EL - c0 < CHUNK ? EL - c0 : CHUNK;
        dim3 g((n + 63) / 64, 4);
        gemm_fused<<<g, 256, 0, stream>>>(zd2, zs2, lrow + c0, lcol + c0,
                                          Wd1_top, Wd1_bot, bdec1, hbuf, n, 1);
        dec2_kernel<<<(n + 3) / 4, 256, 0, stream>>>(hbuf, Wdec2, bdec2, outp + c0, n);
    }
}

// Round 2
// 1338.124 us; speedup vs baseline: 1.8604x; 1.8604x over previous
//
#include <hip/hip_runtime.h>
#include <hip/hip_bf16.h>

#define ND 50000
#define NS 30000
#define NE 1000000
#define EL 200000

typedef short short8 __attribute__((ext_vector_type(8)));
typedef float f32x4 __attribute__((ext_vector_type(4)));

__device__ __forceinline__ float b2f(unsigned short u) {
    union { unsigned int i; float f; } c; c.i = ((unsigned int)u) << 16; return c.f;
}
__device__ __forceinline__ unsigned short f2b(float f) {
    __hip_bfloat16 h = __float2bfloat16(f);   // RNE
    union { __hip_bfloat16 h; unsigned short u; } c; c.h = h; return c.u;
}

// ---------------- CSR build ----------------

__global__ void zero2_kernel(int* a, int na, int* b, int nb) {
    int i = blockIdx.x * blockDim.x + threadIdx.x;
    if (i < na) a[i] = 0;
    if (i < nb) b[i] = 0;
}

__global__ void hist_kernel(const int* __restrict__ src, const int* __restrict__ dst,
                            int* cnt_drug, int* cnt_dis, int n) {
    int i = blockIdx.x * blockDim.x + threadIdx.x;
    if (i < n) {
        atomicAdd(&cnt_dis[dst[i]], 1);
        atomicAdd(&cnt_drug[src[i]], 1);
    }
}

__global__ void scan_kernel(const int* __restrict__ cnt, int* __restrict__ row_ptr,
                            int* __restrict__ cursor, float* __restrict__ inv, int n) {
    __shared__ int sums[256];
    __shared__ int base_sh[256];
    int t = threadIdx.x;
    int chunk = (n + 255) / 256;
    int s0 = t * chunk;
    int s1 = s0 + chunk; if (s1 > n) s1 = n; if (s0 > n) s0 = n;
    int lsum = 0;
    for (int i = s0; i < s1; ++i) lsum += cnt[i];
    sums[t] = lsum;
    __syncthreads();
    if (t == 0) {
        int run = 0;
        for (int i = 0; i < 256; ++i) { base_sh[i] = run; run += sums[i]; }
    }
    __syncthreads();
    int run = base_sh[t];
    for (int i = s0; i < s1; ++i) {
        int c = cnt[i];
        row_ptr[i] = run;
        cursor[i] = run;
        inv[i] = 1.0f / (float)(c > 1 ? c : 1);
        run += c;
    }
    if (t == 255) row_ptr[n] = run;
}

__global__ void scatter_kernel(const int* __restrict__ src, const int* __restrict__ dst,
                               int* cur_drug, int* cur_dis,
                               int* __restrict__ val_sd, int* __restrict__ val_ds, int n) {
    int i = blockIdx.x * blockDim.x + threadIdx.x;
    if (i < n) {
        int s = src[i], d = dst[i];
        int p = atomicAdd(&cur_dis[d], 1);
        val_ds[p] = s;
        int q = atomicAdd(&cur_drug[s], 1);
        val_sd[q] = d;
    }
}

// ---------------- dtype prep ----------------

// fp32 x tables -> bf16 tables, 4 elems/thread, exact grid
__global__ void convert_x(const float* __restrict__ xd, const float* __restrict__ xs,
                          unsigned short* __restrict__ outd, unsigned short* __restrict__ outs) {
    int i = (blockIdx.x * 256 + threadIdx.x) * 4;
    const int NDE = ND * 256;
    if (i < NDE) {
        float4 v = *reinterpret_cast<const float4*>(xd + i);
        ushort4 o; o.x = f2b(v.x); o.y = f2b(v.y); o.z = f2b(v.z); o.w = f2b(v.w);
        *reinterpret_cast<ushort4*>(outd + i) = o;
    } else {
        int j = i - NDE;
        float4 v = *reinterpret_cast<const float4*>(xs + j);
        ushort4 o; o.x = f2b(v.x); o.y = f2b(v.y); o.z = f2b(v.z); o.w = f2b(v.w);
        *reinterpret_cast<ushort4*>(outs + j) = o;
    }
}

struct W10 { const float* p[10]; };

// transpose ten 256x256 fp32 weight blocks into bf16 B^T tables [N][K]
__global__ void transpose_w(W10 s, unsigned short* __restrict__ dst) {
    int o = blockIdx.x * 256 + threadIdx.x;       // 655360 total
    int mat = o >> 16, idx = o & 65535;
    int n = idx >> 8, k = idx & 255;
    dst[o] = f2b(s.p[mat][k * 256 + n]);
}

// ---------------- mean aggregation (bf16 gather, fp32 accum) ----------------

__global__ __launch_bounds__(256) void agg_bf(const unsigned short* __restrict__ xsrc,
                                              const int* __restrict__ row_ptr,
                                              const int* __restrict__ vals,
                                              const float* __restrict__ inv,
                                              unsigned short* __restrict__ outp, int n_dst) {
    int wid = threadIdx.x >> 6, lane = threadIdx.x & 63;
    int node = blockIdx.x * 4 + wid;
    if (node >= n_dst) return;
    int beg = row_ptr[node], end = row_ptr[node + 1];
    const int off = lane * 4;
    float a0 = 0.f, a1 = 0.f, a2 = 0.f, a3 = 0.f;
    for (int j = beg; j < end; ++j) {
        int s = vals[j];
        ushort4 v = *reinterpret_cast<const ushort4*>(xsrc + s * 256 + off);
        a0 += b2f(v.x); a1 += b2f(v.y); a2 += b2f(v.z); a3 += b2f(v.w);
    }
    float iv = inv[node];
    ushort4 o;
    o.x = f2b(a0 * iv); o.y = f2b(a1 * iv); o.z = f2b(a2 * iv); o.w = f2b(a3 * iv);
    *reinterpret_cast<ushort4*>(outp + node * 256 + off) = o;
}

// ---------------- bf16 MFMA GEMM (LDS-free, B pre-transposed) ----------------
// C[M,256] = act( A1@B1 (+ A2@B2) + bias ), all operands bf16, acc fp32.
// Block: 256 thr = 4 waves (2x2), tile 128(M) x 64(N); wave tile 64x32.
// A-frag lane l: row = base + (l&15), k = kc*32 + (l>>4)*8 .. +7  (16B load)
// B-frag lane l: Bt row = col base + (l&15), same k pattern. Identical k-perm
// on both operands -> permutation cancels in the dot product.
// D-frag: row = base + (l>>4)*4 + r, col = base + (l&15)   [verified m89/m91]
__global__ __launch_bounds__(256) void gemm_bf(const unsigned short* __restrict__ A1,
                                               const unsigned short* __restrict__ A2,
                                               const unsigned short* __restrict__ B1t,
                                               const unsigned short* __restrict__ B2t,
                                               const float* __restrict__ bias,
                                               unsigned short* __restrict__ C,
                                               int M, int do_relu) {
    const int t = threadIdx.x;
    const int l = t & 63, w = t >> 6;
    const int wr = w >> 1, wc = w & 1;
    const int fr = l & 15, g = l >> 4;
    const int bm0 = blockIdx.x * 128;
    const int n0 = blockIdx.y * 64 + wc * 32;

    int rowA[4];
#pragma unroll
    for (int m = 0; m < 4; ++m) {
        int r = bm0 + wr * 64 + m * 16 + fr;
        rowA[m] = (r < M ? r : M - 1) * 256;
    }
    const int rowB0 = (n0 + fr) * 256;
    const int rowB1 = (n0 + 16 + fr) * 256;
    const int kbase = g * 8;

    f32x4 acc[4][2];
#pragma unroll
    for (int m = 0; m < 4; ++m)
#pragma unroll
        for (int n = 0; n < 2; ++n)
            acc[m][n] = (f32x4){0.f, 0.f, 0.f, 0.f};

    for (int pass = 0; pass < 2; ++pass) {
        const unsigned short* Ap = pass ? A2 : A1;
        const unsigned short* Bt = pass ? B2t : B1t;
        if (!Ap) break;
#pragma unroll
        for (int kc = 0; kc < 8; ++kc) {
            const int ko = kc * 32 + kbase;
            short8 b0 = *reinterpret_cast<const short8*>(Bt + rowB0 + ko);
            short8 b1 = *reinterpret_cast<const short8*>(Bt + rowB1 + ko);
#pragma unroll
            for (int m = 0; m < 4; ++m) {
                short8 a = *reinterpret_cast<const short8*>(Ap + rowA[m] + ko);
                acc[m][0] = __builtin_amdgcn_mfma_f32_16x16x32_bf16(a, b0, acc[m][0], 0, 0, 0);
                acc[m][1] = __builtin_amdgcn_mfma_f32_16x16x32_bf16(a, b1, acc[m][1], 0, 0, 0);
            }
        }
    }

    // epilogue
#pragma unroll
    for (int n = 0; n < 2; ++n) {
        const int col = n0 + n * 16 + fr;
        const float bv = bias ? bias[col] : 0.0f;
#pragma unroll
        for (int m = 0; m < 4; ++m) {
#pragma unroll
            for (int r = 0; r < 4; ++r) {
                int row = bm0 + wr * 64 + m * 16 + g * 4 + r;
                if (row < M) {
                    float v = acc[m][n][r] + bv;
                    if (do_relu) v = fmaxf(v, 0.f);
                    C[row * 256 + col] = f2b(v);
                }
            }
        }
    }
}

// ---------------- edge decoder: out[e] = relu(Pd[r]+Ps[c]+b1) . w2 + b2 ----------------

__global__ __launch_bounds__(256) void dec_edge(const unsigned short* __restrict__ Pd,
                                                const unsigned short* __restrict__ Ps,
                                                const int* __restrict__ lrow,
                                                const int* __restrict__ lcol,
                                                const float* __restrict__ b1,
                                                const float* __restrict__ w2,
                                                const float* __restrict__ b2,
                                                float* __restrict__ outp, int n) {
    int wid = threadIdx.x >> 6, lane = threadIdx.x & 63;
    int e = blockIdx.x * 4 + wid;
    if (e >= n) return;
    int r = lrow[e], c = lcol[e];
    const int off = lane * 4;
    ushort4 pd = *reinterpret_cast<const ushort4*>(Pd + r * 256 + off);
    ushort4 ps = *reinterpret_cast<const ushort4*>(Ps + c * 256 + off);
    float4 bb = *reinterpret_cast<const float4*>(b1 + off);
    float4 ww = *reinterpret_cast<const float4*>(w2 + off);
    float s = 0.f;
    s += fmaxf(b2f(pd.x) + b2f(ps.x) + bb.x, 0.f) * ww.x;
    s += fmaxf(b2f(pd.y) + b2f(ps.y) + bb.y, 0.f) * ww.y;
    s += fmaxf(b2f(pd.z) + b2f(ps.z) + bb.z, 0.f) * ww.z;
    s += fmaxf(b2f(pd.w) + b2f(ps.w) + bb.w, 0.f) * ww.w;
#pragma unroll
    for (int o = 32; o; o >>= 1) s += __shfl_down(s, o);
    if (lane == 0) outp[e] = s + b2[0];
}

// ---------------- launch ----------------

extern "C" void kernel_launch(void* const* d_in, const int* in_sizes, int n_in,
                              void* d_out, int out_size, void* d_ws, size_t ws_size,
                              hipStream_t stream) {
    const float* x_drug = (const float*)d_in[0];
    const float* x_dis  = (const float*)d_in[1];
    const int* esrc = (const int*)d_in[2];
    const int* edst = (const int*)d_in[3];
    const int* lrow = (const int*)d_in[4];
    const int* lcol = (const int*)d_in[5];
    const float* Wl1_ds = (const float*)d_in[6];
    const float* bl1_ds = (const float*)d_in[7];
    const float* Wr1_ds = (const float*)d_in[8];
    const float* Wl1_sd = (const float*)d_in[9];
    const float* bl1_sd = (const float*)d_in[10];
    const float* Wr1_sd = (const float*)d_in[11];
    const float* Wl2_ds = (const float*)d_in[12];
    const float* bl2_ds = (const float*)d_in[13];
    const float* Wr2_ds = (const float*)d_in[14];
    const float* Wl2_sd = (const float*)d_in[15];
    const float* bl2_sd = (const float*)d_in[16];
    const float* Wr2_sd = (const float*)d_in[17];
    const float* Wdec1 = (const float*)d_in[18];
    const float* bdec1 = (const float*)d_in[19];
    const float* Wdec2 = (const float*)d_in[20];
    const float* bdec2 = (const float*)d_in[21];
    float* outp = (float*)d_out;

    char* ws = (char*)d_ws;
    size_t off = 0;
    auto alloc = [&](size_t bytes) -> void* {
        void* p = ws + off;
        off = (off + bytes + 255) & ~(size_t)255;
        return p;
    };
    int* cnt_dis   = (int*)alloc((size_t)NS * 4);
    int* cnt_drug  = (int*)alloc((size_t)ND * 4);
    int* row_dis   = (int*)alloc((size_t)(NS + 1) * 4);
    int* row_drug  = (int*)alloc((size_t)(ND + 1) * 4);
    int* cur_dis   = (int*)alloc((size_t)NS * 4);
    int* cur_drug  = (int*)alloc((size_t)ND * 4);
    float* inv_dis = (float*)alloc((size_t)NS * 4);
    float* inv_drug= (float*)alloc((size_t)ND * 4);
    int* val_ds    = (int*)alloc((size_t)NE * 4);
    int* val_sd    = (int*)alloc((size_t)NE * 4);
    unsigned short* Wt   = (unsigned short*)alloc((size_t)10 * 65536 * 2);
    unsigned short* xd_b = (unsigned short*)alloc((size_t)ND * 256 * 2);
    unsigned short* xs_b = (unsigned short*)alloc((size_t)NS * 256 * 2);
    unsigned short* aggb = (unsigned short*)alloc((size_t)ND * 256 * 2);
    unsigned short* zd1  = (unsigned short*)alloc((size_t)ND * 256 * 2);
    unsigned short* zs1  = (unsigned short*)alloc((size_t)NS * 256 * 2);
    unsigned short* zd2  = (unsigned short*)alloc((size_t)ND * 256 * 2);
    unsigned short* zs2  = (unsigned short*)alloc((size_t)NS * 256 * 2);
    unsigned short* Pd   = (unsigned short*)alloc((size_t)ND * 256 * 2);
    unsigned short* Ps   = (unsigned short*)alloc((size_t)NS * 256 * 2);

    // --- CSR build ---
    {
        int mx = ND > NS ? ND : NS;
        zero2_kernel<<<(mx + 255) / 256, 256, 0, stream>>>(cnt_dis, NS, cnt_drug, ND);
        hist_kernel<<<(NE + 255) / 256, 256, 0, stream>>>(esrc, edst, cnt_drug, cnt_dis, NE);
        scan_kernel<<<1, 256, 0, stream>>>(cnt_dis, row_dis, cur_dis, inv_dis, NS);
        scan_kernel<<<1, 256, 0, stream>>>(cnt_drug, row_drug, cur_drug, inv_drug, ND);
        scatter_kernel<<<(NE + 255) / 256, 256, 0, stream>>>(esrc, edst, cur_drug, cur_dis,
                                                             val_sd, val_ds, NE);
    }

    // --- dtype prep ---
    convert_x<<<(ND + NS) * 256 / 1024, 256, 0, stream>>>(x_drug, x_dis, xd_b, xs_b);
    W10 wsrc;
    wsrc.p[0] = Wl1_ds; wsrc.p[1] = Wr1_ds; wsrc.p[2] = Wl1_sd; wsrc.p[3] = Wr1_sd;
    wsrc.p[4] = Wl2_ds; wsrc.p[5] = Wr2_ds; wsrc.p[6] = Wl2_sd; wsrc.p[7] = Wr2_sd;
    wsrc.p[8] = Wdec1;                 // rows 0..255  (zd part)
    wsrc.p[9] = Wdec1 + 256 * 256;     // rows 256..511 (zs part)
    transpose_w<<<2560, 256, 0, stream>>>(wsrc, Wt);
    unsigned short* WT[10];
    for (int i = 0; i < 10; ++i) WT[i] = Wt + (size_t)i * 65536;

    dim3 g_ns((NS + 127) / 128, 4);
    dim3 g_nd((ND + 127) / 128, 4);

    // --- layer 1 (relu) ---
    agg_bf<<<(NS + 3) / 4, 256, 0, stream>>>(xd_b, row_dis, val_ds, inv_dis, aggb, NS);
    gemm_bf<<<g_ns, 256, 0, stream>>>(aggb, xs_b, WT[0], WT[1], bl1_ds, zs1, NS, 1);
    agg_bf<<<(ND + 3) / 4, 256, 0, stream>>>(xs_b, row_drug, val_sd, inv_drug, aggb, ND);
    gemm_bf<<<g_nd, 256, 0, stream>>>(aggb, xd_b, WT[2], WT[3], bl1_sd, zd1, ND, 1);

    // --- layer 2 (no relu) ---
    agg_bf<<<(NS + 3) / 4, 256, 0, stream>>>(zd1, row_dis, val_ds, inv_dis, aggb, NS);
    gemm_bf<<<g_ns, 256, 0, stream>>>(aggb, zs1, WT[4], WT[5], bl2_ds, zs2, NS, 0);
    agg_bf<<<(ND + 3) / 4, 256, 0, stream>>>(zs1, row_drug, val_sd, inv_drug, aggb, ND);
    gemm_bf<<<g_nd, 256, 0, stream>>>(aggb, zd1, WT[6], WT[7], bl2_sd, zd2, ND, 0);

    // --- decoder: Pd = zd2 @ W1top, Ps = zs2 @ W1bot (no bias/relu) ---
    gemm_bf<<<g_nd, 256, 0, stream>>>(zd2, nullptr, WT[8], nullptr, nullptr, Pd, ND, 0);
    gemm_bf<<<g_ns, 256, 0, stream>>>(zs2, nullptr, WT[9], nullptr, nullptr, Ps, NS, 0);
    dec_edge<<<(EL + 3) / 4, 256, 0, stream>>>(Pd, Ps, lrow, lcol, bdec1, Wdec2, bdec2, outp, EL);
}

// Round 3
// 947.540 us; speedup vs baseline: 2.6272x; 1.4122x over previous
//
#include <hip/hip_runtime.h>
#include <hip/hip_bf16.h>

#define ND 50000
#define NS 30000
#define NE 1000000
#define EL 200000

typedef short short8 __attribute__((ext_vector_type(8)));
typedef float f32x4 __attribute__((ext_vector_type(4)));

__device__ __forceinline__ float b2f(unsigned short u) {
    union { unsigned int i; float f; } c; c.i = ((unsigned int)u) << 16; return c.f;
}
__device__ __forceinline__ unsigned short f2b(float f) {
    __hip_bfloat16 h = __float2bfloat16(f);   // RNE
    union { __hip_bfloat16 h; unsigned short u; } c; c.h = h; return c.u;
}

// ---------------- CSR build ----------------

__global__ void zero2_kernel(int* a, int na, int* b, int nb) {
    int i = blockIdx.x * blockDim.x + threadIdx.x;
    if (i < na) a[i] = 0;
    if (i < nb) b[i] = 0;
}

// histogram + per-edge rank in one pass (atomic return IS the rank)
__global__ void rank_kernel(const int* __restrict__ src, const int* __restrict__ dst,
                            int* cnt_drug, int* cnt_dis,
                            unsigned short* __restrict__ rank_sd,
                            unsigned short* __restrict__ rank_ds, int n) {
    int i = blockIdx.x * blockDim.x + threadIdx.x;
    if (i < n) {
        int s = src[i], d = dst[i];
        rank_ds[i] = (unsigned short)atomicAdd(&cnt_dis[d], 1);
        rank_sd[i] = (unsigned short)atomicAdd(&cnt_drug[s], 1);
    }
}

// single-block exclusive scan; also emits 1/max(cnt,1)
__global__ void scan_kernel(const int* __restrict__ cnt, int* __restrict__ row_ptr,
                            float* __restrict__ inv, int n) {
    __shared__ int sums[256];
    __shared__ int base_sh[256];
    int t = threadIdx.x;
    int chunk = (n + 255) / 256;
    int s0 = t * chunk;
    int s1 = s0 + chunk; if (s1 > n) s1 = n; if (s0 > n) s0 = n;
    int lsum = 0;
    for (int i = s0; i < s1; ++i) lsum += cnt[i];
    sums[t] = lsum;
    __syncthreads();
    if (t == 0) {
        int run = 0;
        for (int i = 0; i < 256; ++i) { base_sh[i] = run; run += sums[i]; }
    }
    __syncthreads();
    int run = base_sh[t];
    for (int i = s0; i < s1; ++i) {
        int c = cnt[i];
        row_ptr[i] = run;
        inv[i] = 1.0f / (float)(c > 1 ? c : 1);
        run += c;
    }
    if (t == 255) row_ptr[n] = run;
}

// place edges: plain stores, no atomic dependency; u16 payload
__global__ void place_kernel(const int* __restrict__ src, const int* __restrict__ dst,
                             const int* __restrict__ row_drug, const int* __restrict__ row_dis,
                             const unsigned short* __restrict__ rank_sd,
                             const unsigned short* __restrict__ rank_ds,
                             unsigned short* __restrict__ val_sd,
                             unsigned short* __restrict__ val_ds, int n) {
    int i = blockIdx.x * blockDim.x + threadIdx.x;
    if (i < n) {
        int s = src[i], d = dst[i];
        val_ds[row_dis[d] + (int)rank_ds[i]] = (unsigned short)s;
        val_sd[row_drug[s] + (int)rank_sd[i]] = (unsigned short)d;
    }
}

// ---------------- dtype prep ----------------

__global__ void convert_x(const float* __restrict__ xd, const float* __restrict__ xs,
                          unsigned short* __restrict__ outd, unsigned short* __restrict__ outs) {
    int i = (blockIdx.x * 256 + threadIdx.x) * 4;
    const int NDE = ND * 256;
    if (i < NDE) {
        float4 v = *reinterpret_cast<const float4*>(xd + i);
        ushort4 o; o.x = f2b(v.x); o.y = f2b(v.y); o.z = f2b(v.z); o.w = f2b(v.w);
        *reinterpret_cast<ushort4*>(outd + i) = o;
    } else {
        int j = i - NDE;
        float4 v = *reinterpret_cast<const float4*>(xs + j);
        ushort4 o; o.x = f2b(v.x); o.y = f2b(v.y); o.z = f2b(v.z); o.w = f2b(v.w);
        *reinterpret_cast<ushort4*>(outs + j) = o;
    }
}

struct W10 { const float* p[10]; };

// transpose ten 256x256 fp32 weight blocks into bf16 B^T tables [N][K]
__global__ void transpose_w(W10 s, unsigned short* __restrict__ dst) {
    int o = blockIdx.x * 256 + threadIdx.x;       // 655360 total
    int mat = o >> 16, idx = o & 65535;
    int n = idx >> 8, k = idx & 255;
    dst[o] = f2b(s.p[mat][k * 256 + n]);
}

// ---------------- mean aggregation (bf16 gather, fp32 accum, 4-deep) ----------------

__global__ __launch_bounds__(256) void agg_bf(const unsigned short* __restrict__ xsrc,
                                              const int* __restrict__ row_ptr,
                                              const unsigned short* __restrict__ vals,
                                              const float* __restrict__ inv,
                                              unsigned short* __restrict__ outp, int n_dst) {
    int wid = threadIdx.x >> 6, lane = threadIdx.x & 63;
    int node = blockIdx.x * 4 + wid;
    if (node >= n_dst) return;
    int beg = row_ptr[node], end = row_ptr[node + 1];
    const int off = lane * 4;
    float a0 = 0.f, a1 = 0.f, a2 = 0.f, a3 = 0.f;
    int j = beg;
    for (; j + 4 <= end; j += 4) {
        int s0 = vals[j], s1 = vals[j + 1], s2 = vals[j + 2], s3 = vals[j + 3];
        ushort4 v0 = *reinterpret_cast<const ushort4*>(xsrc + s0 * 256 + off);
        ushort4 v1 = *reinterpret_cast<const ushort4*>(xsrc + s1 * 256 + off);
        ushort4 v2 = *reinterpret_cast<const ushort4*>(xsrc + s2 * 256 + off);
        ushort4 v3 = *reinterpret_cast<const ushort4*>(xsrc + s3 * 256 + off);
        a0 += b2f(v0.x) + b2f(v1.x) + b2f(v2.x) + b2f(v3.x);
        a1 += b2f(v0.y) + b2f(v1.y) + b2f(v2.y) + b2f(v3.y);
        a2 += b2f(v0.z) + b2f(v1.z) + b2f(v2.z) + b2f(v3.z);
        a3 += b2f(v0.w) + b2f(v1.w) + b2f(v2.w) + b2f(v3.w);
    }
    for (; j < end; ++j) {
        int s = vals[j];
        ushort4 v = *reinterpret_cast<const ushort4*>(xsrc + s * 256 + off);
        a0 += b2f(v.x); a1 += b2f(v.y); a2 += b2f(v.z); a3 += b2f(v.w);
    }
    float iv = inv[node];
    ushort4 o;
    o.x = f2b(a0 * iv); o.y = f2b(a1 * iv); o.z = f2b(a2 * iv); o.w = f2b(a3 * iv);
    *reinterpret_cast<ushort4*>(outp + node * 256 + off) = o;
}

// ---------------- bf16 MFMA GEMM (LDS-free, B pre-transposed) ----------------
// C[M,256] = act( A1@B1 (+ A2@B2) + bias ). Tile 128(M) x 128(N), 4 waves 2x2,
// wave tile 64x64, acc[4][4]. A read 2x total (grid.y = 2).
__global__ __launch_bounds__(256) void gemm_bf(const unsigned short* __restrict__ A1,
                                               const unsigned short* __restrict__ A2,
                                               const unsigned short* __restrict__ B1t,
                                               const unsigned short* __restrict__ B2t,
                                               const float* __restrict__ bias,
                                               unsigned short* __restrict__ C,
                                               int M, int do_relu) {
    const int t = threadIdx.x;
    const int l = t & 63, w = t >> 6;
    const int wr = w >> 1, wc = w & 1;
    const int fr = l & 15, g = l >> 4;
    const int bm0 = blockIdx.x * 128;
    const int n0 = blockIdx.y * 128 + wc * 64;

    int rowA[4];
#pragma unroll
    for (int m = 0; m < 4; ++m) {
        int r = bm0 + wr * 64 + m * 16 + fr;
        rowA[m] = (r < M ? r : M - 1) * 256;
    }
    int rowB[4];
#pragma unroll
    for (int n = 0; n < 4; ++n) rowB[n] = (n0 + n * 16 + fr) * 256;
    const int kbase = g * 8;

    f32x4 acc[4][4];
#pragma unroll
    for (int m = 0; m < 4; ++m)
#pragma unroll
        for (int n = 0; n < 4; ++n)
            acc[m][n] = (f32x4){0.f, 0.f, 0.f, 0.f};

    for (int pass = 0; pass < 2; ++pass) {
        const unsigned short* Ap = pass ? A2 : A1;
        const unsigned short* Bt = pass ? B2t : B1t;
        if (!Ap) break;
#pragma unroll
        for (int kc = 0; kc < 8; ++kc) {
            const int ko = kc * 32 + kbase;
            short8 b[4], a[4];
#pragma unroll
            for (int n = 0; n < 4; ++n)
                b[n] = *reinterpret_cast<const short8*>(Bt + rowB[n] + ko);
#pragma unroll
            for (int m = 0; m < 4; ++m)
                a[m] = *reinterpret_cast<const short8*>(Ap + rowA[m] + ko);
#pragma unroll
            for (int m = 0; m < 4; ++m)
#pragma unroll
                for (int n = 0; n < 4; ++n)
                    acc[m][n] = __builtin_amdgcn_mfma_f32_16x16x32_bf16(a[m], b[n], acc[m][n], 0, 0, 0);
        }
    }

    // epilogue: D row = base + g*4 + r, col = base + fr  [verified m89/m91]
#pragma unroll
    for (int n = 0; n < 4; ++n) {
        const int col = n0 + n * 16 + fr;
        const float bv = bias ? bias[col] : 0.0f;
#pragma unroll
        for (int m = 0; m < 4; ++m) {
#pragma unroll
            for (int r = 0; r < 4; ++r) {
                int row = bm0 + wr * 64 + m * 16 + g * 4 + r;
                if (row < M) {
                    float v = acc[m][n][r] + bv;
                    if (do_relu) v = fmaxf(v, 0.f);
                    C[row * 256 + col] = f2b(v);
                }
            }
        }
    }
}

// ---------------- edge decoder: out[e] = relu(Pd[r]+Ps[c]+b1) . w2 + b2 ----------------

__global__ __launch_bounds__(256) void dec_edge(const unsigned short* __restrict__ Pd,
                                                const unsigned short* __restrict__ Ps,
                                                const int* __restrict__ lrow,
                                                const int* __restrict__ lcol,
                                                const float* __restrict__ b1,
                                                const float* __restrict__ w2,
                                                const float* __restrict__ b2,
                                                float* __restrict__ outp, int n) {
    int wid = threadIdx.x >> 6, lane = threadIdx.x & 63;
    int e = blockIdx.x * 4 + wid;
    if (e >= n) return;
    int r = lrow[e], c = lcol[e];
    const int off = lane * 4;
    ushort4 pd = *reinterpret_cast<const ushort4*>(Pd + r * 256 + off);
    ushort4 ps = *reinterpret_cast<const ushort4*>(Ps + c * 256 + off);
    float4 bb = *reinterpret_cast<const float4*>(b1 + off);
    float4 ww = *reinterpret_cast<const float4*>(w2 + off);
    float s = 0.f;
    s += fmaxf(b2f(pd.x) + b2f(ps.x) + bb.x, 0.f) * ww.x;
    s += fmaxf(b2f(pd.y) + b2f(ps.y) + bb.y, 0.f) * ww.y;
    s += fmaxf(b2f(pd.z) + b2f(ps.z) + bb.z, 0.f) * ww.z;
    s += fmaxf(b2f(pd.w) + b2f(ps.w) + bb.w, 0.f) * ww.w;
#pragma unroll
    for (int o = 32; o; o >>= 1) s += __shfl_down(s, o);
    if (lane == 0) outp[e] = s + b2[0];
}

// ---------------- launch ----------------

extern "C" void kernel_launch(void* const* d_in, const int* in_sizes, int n_in,
                              void* d_out, int out_size, void* d_ws, size_t ws_size,
                              hipStream_t stream) {
    const float* x_drug = (const float*)d_in[0];
    const float* x_dis  = (const float*)d_in[1];
    const int* esrc = (const int*)d_in[2];
    const int* edst = (const int*)d_in[3];
    const int* lrow = (const int*)d_in[4];
    const int* lcol = (const int*)d_in[5];
    const float* Wl1_ds = (const float*)d_in[6];
    const float* bl1_ds = (const float*)d_in[7];
    const float* Wr1_ds = (const float*)d_in[8];
    const float* Wl1_sd = (const float*)d_in[9];
    const float* bl1_sd = (const float*)d_in[10];
    const float* Wr1_sd = (const float*)d_in[11];
    const float* Wl2_ds = (const float*)d_in[12];
    const float* bl2_ds = (const float*)d_in[13];
    const float* Wr2_ds = (const float*)d_in[14];
    const float* Wl2_sd = (const float*)d_in[15];
    const float* bl2_sd = (const float*)d_in[16];
    const float* Wr2_sd = (const float*)d_in[17];
    const float* Wdec1 = (const float*)d_in[18];
    const float* bdec1 = (const float*)d_in[19];
    const float* Wdec2 = (const float*)d_in[20];
    const float* bdec2 = (const float*)d_in[21];
    float* outp = (float*)d_out;

    char* ws = (char*)d_ws;
    size_t off = 0;
    auto alloc = [&](size_t bytes) -> void* {
        void* p = ws + off;
        off = (off + bytes + 255) & ~(size_t)255;
        return p;
    };
    int* cnt_dis   = (int*)alloc((size_t)NS * 4);
    int* cnt_drug  = (int*)alloc((size_t)ND * 4);
    int* row_dis   = (int*)alloc((size_t)(NS + 1) * 4);
    int* row_drug  = (int*)alloc((size_t)(ND + 1) * 4);
    float* inv_dis = (float*)alloc((size_t)NS * 4);
    float* inv_drug= (float*)alloc((size_t)ND * 4);
    unsigned short* rank_ds = (unsigned short*)alloc((size_t)NE * 2);
    unsigned short* rank_sd = (unsigned short*)alloc((size_t)NE * 2);
    unsigned short* val_ds  = (unsigned short*)alloc((size_t)NE * 2);
    unsigned short* val_sd  = (unsigned short*)alloc((size_t)NE * 2);
    unsigned short* Wt   = (unsigned short*)alloc((size_t)10 * 65536 * 2);
    unsigned short* xd_b = (unsigned short*)alloc((size_t)ND * 256 * 2);
    unsigned short* xs_b = (unsigned short*)alloc((size_t)NS * 256 * 2);
    unsigned short* aggb = (unsigned short*)alloc((size_t)ND * 256 * 2);
    unsigned short* zd1  = (unsigned short*)alloc((size_t)ND * 256 * 2);
    unsigned short* zs1  = (unsigned short*)alloc((size_t)NS * 256 * 2);
    unsigned short* zd2  = (unsigned short*)alloc((size_t)ND * 256 * 2);
    unsigned short* zs2  = (unsigned short*)alloc((size_t)NS * 256 * 2);
    unsigned short* Pd   = (unsigned short*)alloc((size_t)ND * 256 * 2);
    unsigned short* Ps   = (unsigned short*)alloc((size_t)NS * 256 * 2);

    // --- CSR build ---
    {
        int mx = ND > NS ? ND : NS;
        zero2_kernel<<<(mx + 255) / 256, 256, 0, stream>>>(cnt_dis, NS, cnt_drug, ND);
        rank_kernel<<<(NE + 255) / 256, 256, 0, stream>>>(esrc, edst, cnt_drug, cnt_dis,
                                                          rank_sd, rank_ds, NE);
        scan_kernel<<<1, 256, 0, stream>>>(cnt_dis, row_dis, inv_dis, NS);
        scan_kernel<<<1, 256, 0, stream>>>(cnt_drug, row_drug, inv_drug, ND);
        place_kernel<<<(NE + 255) / 256, 256, 0, stream>>>(esrc, edst, row_drug, row_dis,
                                                           rank_sd, rank_ds, val_sd, val_ds, NE);
    }

    // --- dtype prep ---
    convert_x<<<(ND + NS) * 256 / 1024, 256, 0, stream>>>(x_drug, x_dis, xd_b, xs_b);
    W10 wsrc;
    wsrc.p[0] = Wl1_ds; wsrc.p[1] = Wr1_ds; wsrc.p[2] = Wl1_sd; wsrc.p[3] = Wr1_sd;
    wsrc.p[4] = Wl2_ds; wsrc.p[5] = Wr2_ds; wsrc.p[6] = Wl2_sd; wsrc.p[7] = Wr2_sd;
    wsrc.p[8] = Wdec1;                 // rows 0..255  (zd part)
    wsrc.p[9] = Wdec1 + 256 * 256;     // rows 256..511 (zs part)
    transpose_w<<<2560, 256, 0, stream>>>(wsrc, Wt);
    unsigned short* WT[10];
    for (int i = 0; i < 10; ++i) WT[i] = Wt + (size_t)i * 65536;

    dim3 g_ns((NS + 127) / 128, 2);
    dim3 g_nd((ND + 127) / 128, 2);

    // --- layer 1 (relu) ---
    agg_bf<<<(NS + 3) / 4, 256, 0, stream>>>(xd_b, row_dis, val_ds, inv_dis, aggb, NS);
    gemm_bf<<<g_ns, 256, 0, stream>>>(aggb, xs_b, WT[0], WT[1], bl1_ds, zs1, NS, 1);
    agg_bf<<<(ND + 3) / 4, 256, 0, stream>>>(xs_b, row_drug, val_sd, inv_drug, aggb, ND);
    gemm_bf<<<g_nd, 256, 0, stream>>>(aggb, xd_b, WT[2], WT[3], bl1_sd, zd1, ND, 1);

    // --- layer 2 (no relu) ---
    agg_bf<<<(NS + 3) / 4, 256, 0, stream>>>(zd1, row_dis, val_ds, inv_dis, aggb, NS);
    gemm_bf<<<g_ns, 256, 0, stream>>>(aggb, zs1, WT[4], WT[5], bl2_ds, zs2, NS, 0);
    agg_bf<<<(ND + 3) / 4, 256, 0, stream>>>(zs1, row_drug, val_sd, inv_drug, aggb, ND);
    gemm_bf<<<g_nd, 256, 0, stream>>>(aggb, zd1, WT[6], WT[7], bl2_sd, zd2, ND, 0);

    // --- decoder: Pd = zd2 @ W1top, Ps = zs2 @ W1bot (no bias/relu) ---
    gemm_bf<<<g_nd, 256, 0, stream>>>(zd2, nullptr, WT[8], nullptr, nullptr, Pd, ND, 0);
    gemm_bf<<<g_ns, 256, 0, stream>>>(zs2, nullptr, WT[9], nullptr, nullptr, Ps, NS, 0);
    dec_edge<<<(EL + 3) / 4, 256, 0, stream>>>(Pd, Ps, lrow, lcol, bdec1, Wdec2, bdec2, outp, EL);
}

// Round 4
// 704.864 us; speedup vs baseline: 3.5317x; 1.3443x over previous
//
#include <hip/hip_runtime.h>
#include <hip/hip_bf16.h>

#define ND 50000
#define NS 30000
#define NE 1000000
#define EL 200000
#define NTOT (NS + ND)          // 80000
#define SCAN_BLK ((NTOT + 1023) / 1024)   // 79

typedef short short8 __attribute__((ext_vector_type(8)));
typedef float f32x4 __attribute__((ext_vector_type(4)));

__device__ __forceinline__ float b2f(unsigned short u) {
    union { unsigned int i; float f; } c; c.i = ((unsigned int)u) << 16; return c.f;
}
__device__ __forceinline__ unsigned short f2b(float f) {
    __hip_bfloat16 h = __float2bfloat16(f);   // RNE
    union { __hip_bfloat16 h; unsigned short u; } c; c.h = h; return c.u;
}

// ---------------- CSR build ----------------

__global__ void zero_kernel(int* a, int n) {
    int i = blockIdx.x * blockDim.x + threadIdx.x;
    if (i < n) a[i] = 0;
}

// histogram + per-edge rank in one pass (atomic return IS the rank)
__global__ void rank_kernel(const int* __restrict__ src, const int* __restrict__ dst,
                            int* cnt_drug, int* cnt_dis,
                            unsigned short* __restrict__ rank_sd,
                            unsigned short* __restrict__ rank_ds, int n) {
    int i = blockIdx.x * blockDim.x + threadIdx.x;
    if (i < n) {
        int s = src[i], d = dst[i];
        rank_ds[i] = (unsigned short)atomicAdd(&cnt_dis[d], 1);
        rank_sd[i] = (unsigned short)atomicAdd(&cnt_drug[s], 1);
    }
}

// hierarchical scan over concatenated [cnt_dis | cnt_drug] (NTOT ints)
__global__ __launch_bounds__(256) void scan_part(const int* __restrict__ cnt,
                                                 int* __restrict__ bsum) {
    __shared__ int red[4];
    int t = threadIdx.x, lane = t & 63, wid = t >> 6;
    int base = blockIdx.x * 1024 + t * 4;
    int s = 0;
    if (base < NTOT) {           // NTOT % 4 == 0 -> whole int4 in bounds
        int4 c = *reinterpret_cast<const int4*>(cnt + base);
        s = c.x + c.y + c.z + c.w;
    }
#pragma unroll
    for (int off = 32; off; off >>= 1) s += __shfl_down(s, off);
    if (lane == 0) red[wid] = s;
    __syncthreads();
    if (t == 0) bsum[blockIdx.x] = red[0] + red[1] + red[2] + red[3];
}

__global__ void scan_top(int* bsum, int nb) {   // 1 block x 64 threads, nb <= 128
    int lane = threadIdx.x;
    int a0 = lane < nb ? bsum[lane] : 0;
    int a1 = (64 + lane) < nb ? bsum[64 + lane] : 0;
    int i0 = a0, i1 = a1;
#pragma unroll
    for (int off = 1; off < 64; off <<= 1) {
        int t0 = __shfl_up(i0, off);
        int t1 = __shfl_up(i1, off);
        if (lane >= off) { i0 += t0; i1 += t1; }
    }
    int tot0 = __shfl(i0, 63);
    if (lane < nb) bsum[lane] = i0 - a0;                    // exclusive
    if (64 + lane < nb) bsum[64 + lane] = tot0 + i1 - a1;
}

__global__ __launch_bounds__(256) void scan_emit(const int* __restrict__ cnt,
                                                 const int* __restrict__ boff,
                                                 int* __restrict__ row_dis,
                                                 int* __restrict__ row_drug,
                                                 float* __restrict__ inv_dis,
                                                 float* __restrict__ inv_drug) {
    __shared__ int wsum[4];
    int t = threadIdx.x, lane = t & 63, wid = t >> 6;
    int base = blockIdx.x * 1024 + t * 4;
    int4 c = make_int4(0, 0, 0, 0);
    if (base < NTOT) c = *reinterpret_cast<const int4*>(cnt + base);
    int sl = c.x + c.y + c.z + c.w;
    int sc = sl;
#pragma unroll
    for (int off = 1; off < 64; off <<= 1) {
        int tv = __shfl_up(sc, off);
        if (lane >= off) sc += tv;
    }
    if (lane == 63) wsum[wid] = sc;
    __syncthreads();
    int woff = 0;
    for (int w2 = 0; w2 < wid; ++w2) woff += wsum[w2];
    int run = boff[blockIdx.x] + woff + (sc - sl);   // exclusive prefix of this thread's 1st elem
    int cc[4] = { c.x, c.y, c.z, c.w };
    if (base < NTOT) {
#pragma unroll
        for (int k = 0; k < 4; ++k) {
            int i = base + k;
            float iv = 1.0f / (float)(cc[k] > 1 ? cc[k] : 1);
            if (i < NS) { row_dis[i] = run; inv_dis[i] = iv; }
            else        { row_drug[i - NS] = run - NE; inv_drug[i - NS] = iv; }
            run += cc[k];
        }
    }
    if (blockIdx.x == 0 && t == 0) { row_dis[NS] = NE; row_drug[ND] = NE; }
}

// place edges: plain stores, no atomic dependency; u16 payload
__global__ void place_kernel(const int* __restrict__ src, const int* __restrict__ dst,
                             const int* __restrict__ row_drug, const int* __restrict__ row_dis,
                             const unsigned short* __restrict__ rank_sd,
                             const unsigned short* __restrict__ rank_ds,
                             unsigned short* __restrict__ val_sd,
                             unsigned short* __restrict__ val_ds, int n) {
    int i = blockIdx.x * blockDim.x + threadIdx.x;
    if (i < n) {
        int s = src[i], d = dst[i];
        val_ds[row_dis[d] + (int)rank_ds[i]] = (unsigned short)s;
        val_sd[row_drug[s] + (int)rank_sd[i]] = (unsigned short)d;
    }
}

// ---------------- dtype prep ----------------

__global__ void convert_x(const float* __restrict__ xd, const float* __restrict__ xs,
                          unsigned short* __restrict__ outd, unsigned short* __restrict__ outs) {
    int i = (blockIdx.x * 256 + threadIdx.x) * 4;
    const int NDE = ND * 256;
    if (i < NDE) {
        float4 v = *reinterpret_cast<const float4*>(xd + i);
        ushort4 o; o.x = f2b(v.x); o.y = f2b(v.y); o.z = f2b(v.z); o.w = f2b(v.w);
        *reinterpret_cast<ushort4*>(outd + i) = o;
    } else {
        int j = i - NDE;
        float4 v = *reinterpret_cast<const float4*>(xs + j);
        ushort4 o; o.x = f2b(v.x); o.y = f2b(v.y); o.z = f2b(v.z); o.w = f2b(v.w);
        *reinterpret_cast<ushort4*>(outs + j) = o;
    }
}

struct W10 { const float* p[10]; };

// transpose ten 256x256 fp32 weight blocks into bf16 B^T tables [N][K]
__global__ void transpose_w(W10 s, unsigned short* __restrict__ dst) {
    int o = blockIdx.x * 256 + threadIdx.x;       // 655360 total
    int mat = o >> 16, idx = o & 65535;
    int n = idx >> 8, k = idx & 255;
    dst[o] = f2b(s.p[mat][k * 256 + n]);
}

// ---------------- fused mean aggregation: both directions in one dispatch ----------------

__global__ __launch_bounds__(256) void agg_bf2(const unsigned short* __restrict__ srcDis,  // drug feats (dis-dst)
                                               const unsigned short* __restrict__ srcDrug, // dis feats (drug-dst)
                                               const int* __restrict__ row_dis,
                                               const int* __restrict__ row_drug,
                                               const unsigned short* __restrict__ val_ds,
                                               const unsigned short* __restrict__ val_sd,
                                               const float* __restrict__ inv_dis,
                                               const float* __restrict__ inv_drug,
                                               unsigned short* __restrict__ outDis,
                                               unsigned short* __restrict__ outDrug) {
    int wid = threadIdx.x >> 6, lane = threadIdx.x & 63;
    int node = blockIdx.x * 4 + wid;
    const unsigned short* xsrc; const int* row; const unsigned short* vals;
    const float* inv; unsigned short* outp;
    if (node < NS) {
        xsrc = srcDis; row = row_dis; vals = val_ds; inv = inv_dis; outp = outDis;
    } else {
        node -= NS;
        if (node >= ND) return;
        xsrc = srcDrug; row = row_drug; vals = val_sd; inv = inv_drug; outp = outDrug;
    }
    int beg = row[node], end = row[node + 1];
    const int off = lane * 4;
    float a0 = 0.f, a1 = 0.f, a2 = 0.f, a3 = 0.f;
    int j = beg;
    for (; j + 4 <= end; j += 4) {
        int s0 = vals[j], s1 = vals[j + 1], s2 = vals[j + 2], s3 = vals[j + 3];
        ushort4 v0 = *reinterpret_cast<const ushort4*>(xsrc + s0 * 256 + off);
        ushort4 v1 = *reinterpret_cast<const ushort4*>(xsrc + s1 * 256 + off);
        ushort4 v2 = *reinterpret_cast<const ushort4*>(xsrc + s2 * 256 + off);
        ushort4 v3 = *reinterpret_cast<const ushort4*>(xsrc + s3 * 256 + off);
        a0 += b2f(v0.x) + b2f(v1.x) + b2f(v2.x) + b2f(v3.x);
        a1 += b2f(v0.y) + b2f(v1.y) + b2f(v2.y) + b2f(v3.y);
        a2 += b2f(v0.z) + b2f(v1.z) + b2f(v2.z) + b2f(v3.z);
        a3 += b2f(v0.w) + b2f(v1.w) + b2f(v2.w) + b2f(v3.w);
    }
    for (; j < end; ++j) {
        int s = vals[j];
        ushort4 v = *reinterpret_cast<const ushort4*>(xsrc + s * 256 + off);
        a0 += b2f(v.x); a1 += b2f(v.y); a2 += b2f(v.z); a3 += b2f(v.w);
    }
    float iv = inv[node];
    ushort4 o;
    o.x = f2b(a0 * iv); o.y = f2b(a1 * iv); o.z = f2b(a2 * iv); o.w = f2b(a3 * iv);
    *reinterpret_cast<ushort4*>(outp + node * 256 + off) = o;
}

// ---------------- bf16 MFMA GEMM, two segments per dispatch ----------------
// Per segment: C[M,256] = act( A1@B1 (+ A2@B2) + bias ). Tile 128x128, 4 waves 2x2.

struct GemmSeg {
    const unsigned short* A1;
    const unsigned short* A2;
    const unsigned short* B1t;
    const unsigned short* B2t;
    const float* bias;
    unsigned short* C;
    int M; int relu; int nblk;
};

__global__ __launch_bounds__(256) void gemm_bf2(GemmSeg sa, GemmSeg sb) {
    GemmSeg s;
    int bx = blockIdx.x;
    if (bx < sa.nblk) s = sa;
    else { s = sb; bx -= sa.nblk; }

    const int t = threadIdx.x;
    const int l = t & 63, w = t >> 6;
    const int wr = w >> 1, wc = w & 1;
    const int fr = l & 15, g = l >> 4;
    const int bm0 = bx * 128;
    const int n0 = blockIdx.y * 128 + wc * 64;
    const int M = s.M;

    int rowA[4];
#pragma unroll
    for (int m = 0; m < 4; ++m) {
        int r = bm0 + wr * 64 + m * 16 + fr;
        rowA[m] = (r < M ? r : M - 1) * 256;
    }
    int rowB[4];
#pragma unroll
    for (int n = 0; n < 4; ++n) rowB[n] = (n0 + n * 16 + fr) * 256;
    const int kbase = g * 8;

    f32x4 acc[4][4];
#pragma unroll
    for (int m = 0; m < 4; ++m)
#pragma unroll
        for (int n = 0; n < 4; ++n)
            acc[m][n] = (f32x4){0.f, 0.f, 0.f, 0.f};

    for (int pass = 0; pass < 2; ++pass) {
        const unsigned short* Ap = pass ? s.A2 : s.A1;
        const unsigned short* Bt = pass ? s.B2t : s.B1t;
        if (!Ap) break;
#pragma unroll
        for (int kc = 0; kc < 8; ++kc) {
            const int ko = kc * 32 + kbase;
            short8 b[4], a[4];
#pragma unroll
            for (int n = 0; n < 4; ++n)
                b[n] = *reinterpret_cast<const short8*>(Bt + rowB[n] + ko);
#pragma unroll
            for (int m = 0; m < 4; ++m)
                a[m] = *reinterpret_cast<const short8*>(Ap + rowA[m] + ko);
#pragma unroll
            for (int m = 0; m < 4; ++m)
#pragma unroll
                for (int n = 0; n < 4; ++n)
                    acc[m][n] = __builtin_amdgcn_mfma_f32_16x16x32_bf16(a[m], b[n], acc[m][n], 0, 0, 0);
        }
    }

    // epilogue: D row = base + g*4 + r, col = base + fr  [verified m89/m91]
#pragma unroll
    for (int n = 0; n < 4; ++n) {
        const int col = n0 + n * 16 + fr;
        const float bv = s.bias ? s.bias[col] : 0.0f;
#pragma unroll
        for (int m = 0; m < 4; ++m) {
#pragma unroll
            for (int r = 0; r < 4; ++r) {
                int row = bm0 + wr * 64 + m * 16 + g * 4 + r;
                if (row < M) {
                    float v = acc[m][n][r] + bv;
                    if (s.relu) v = fmaxf(v, 0.f);
                    s.C[row * 256 + col] = f2b(v);
                }
            }
        }
    }
}

// ---------------- edge decoder: out[e] = relu(Pd[r]+Ps[c]+b1) . w2 + b2 ----------------

__global__ __launch_bounds__(256) void dec_edge(const unsigned short* __restrict__ Pd,
                                                const unsigned short* __restrict__ Ps,
                                                const int* __restrict__ lrow,
                                                const int* __restrict__ lcol,
                                                const float* __restrict__ b1,
                                                const float* __restrict__ w2,
                                                const float* __restrict__ b2,
                                                float* __restrict__ outp, int n) {
    int wid = threadIdx.x >> 6, lane = threadIdx.x & 63;
    int e = blockIdx.x * 4 + wid;
    if (e >= n) return;
    int r = lrow[e], c = lcol[e];
    const int off = lane * 4;
    ushort4 pd = *reinterpret_cast<const ushort4*>(Pd + r * 256 + off);
    ushort4 ps = *reinterpret_cast<const ushort4*>(Ps + c * 256 + off);
    float4 bb = *reinterpret_cast<const float4*>(b1 + off);
    float4 ww = *reinterpret_cast<const float4*>(w2 + off);
    float s = 0.f;
    s += fmaxf(b2f(pd.x) + b2f(ps.x) + bb.x, 0.f) * ww.x;
    s += fmaxf(b2f(pd.y) + b2f(ps.y) + bb.y, 0.f) * ww.y;
    s += fmaxf(b2f(pd.z) + b2f(ps.z) + bb.z, 0.f) * ww.z;
    s += fmaxf(b2f(pd.w) + b2f(ps.w) + bb.w, 0.f) * ww.w;
#pragma unroll
    for (int o = 32; o; o >>= 1) s += __shfl_down(s, o);
    if (lane == 0) outp[e] = s + b2[0];
}

// ---------------- launch ----------------

extern "C" void kernel_launch(void* const* d_in, const int* in_sizes, int n_in,
                              void* d_out, int out_size, void* d_ws, size_t ws_size,
                              hipStream_t stream) {
    const float* x_drug = (const float*)d_in[0];
    const float* x_dis  = (const float*)d_in[1];
    const int* esrc = (const int*)d_in[2];
    const int* edst = (const int*)d_in[3];
    const int* lrow = (const int*)d_in[4];
    const int* lcol = (const int*)d_in[5];
    const float* Wl1_ds = (const float*)d_in[6];
    const float* bl1_ds = (const float*)d_in[7];
    const float* Wr1_ds = (const float*)d_in[8];
    const float* Wl1_sd = (const float*)d_in[9];
    const float* bl1_sd = (const float*)d_in[10];
    const float* Wr1_sd = (const float*)d_in[11];
    const float* Wl2_ds = (const float*)d_in[12];
    const float* bl2_ds = (const float*)d_in[13];
    const float* Wr2_ds = (const float*)d_in[14];
    const float* Wl2_sd = (const float*)d_in[15];
    const float* bl2_sd = (const float*)d_in[16];
    const float* Wr2_sd = (const float*)d_in[17];
    const float* Wdec1 = (const float*)d_in[18];
    const float* bdec1 = (const float*)d_in[19];
    const float* Wdec2 = (const float*)d_in[20];
    const float* bdec2 = (const float*)d_in[21];
    float* outp = (float*)d_out;

    char* ws = (char*)d_ws;
    size_t off = 0;
    auto alloc = [&](size_t bytes) -> void* {
        void* p = ws + off;
        off = (off + bytes + 255) & ~(size_t)255;
        return p;
    };
    int* cnt       = (int*)alloc((size_t)NTOT * 4);      // [cnt_dis | cnt_drug]
    int* bsum      = (int*)alloc((size_t)SCAN_BLK * 4);
    int* row_dis   = (int*)alloc((size_t)(NS + 1) * 4);
    int* row_drug  = (int*)alloc((size_t)(ND + 1) * 4);
    float* inv_dis = (float*)alloc((size_t)NS * 4);
    float* inv_drug= (float*)alloc((size_t)ND * 4);
    unsigned short* rank_ds = (unsigned short*)alloc((size_t)NE * 2);
    unsigned short* rank_sd = (unsigned short*)alloc((size_t)NE * 2);
    unsigned short* val_ds  = (unsigned short*)alloc((size_t)NE * 2);
    unsigned short* val_sd  = (unsigned short*)alloc((size_t)NE * 2);
    unsigned short* Wt   = (unsigned short*)alloc((size_t)10 * 65536 * 2);
    unsigned short* xd_b = (unsigned short*)alloc((size_t)ND * 256 * 2);
    unsigned short* xs_b = (unsigned short*)alloc((size_t)NS * 256 * 2);
    unsigned short* aggs = (unsigned short*)alloc((size_t)NS * 256 * 2);  // dis-dst agg
    unsigned short* aggd = (unsigned short*)alloc((size_t)ND * 256 * 2);  // drug-dst agg
    unsigned short* zd1  = (unsigned short*)alloc((size_t)ND * 256 * 2);
    unsigned short* zs1  = (unsigned short*)alloc((size_t)NS * 256 * 2);
    unsigned short* zd2  = (unsigned short*)alloc((size_t)ND * 256 * 2);
    unsigned short* zs2  = (unsigned short*)alloc((size_t)NS * 256 * 2);
    unsigned short* Pd   = (unsigned short*)alloc((size_t)ND * 256 * 2);
    unsigned short* Ps   = (unsigned short*)alloc((size_t)NS * 256 * 2);
    int* cnt_dis = cnt;
    int* cnt_drug = cnt + NS;

    // --- dtype prep (independent of CSR) ---
    convert_x<<<(ND + NS) * 256 / 1024, 256, 0, stream>>>(x_drug, x_dis, xd_b, xs_b);
    W10 wsrc;
    wsrc.p[0] = Wl1_ds; wsrc.p[1] = Wr1_ds; wsrc.p[2] = Wl1_sd; wsrc.p[3] = Wr1_sd;
    wsrc.p[4] = Wl2_ds; wsrc.p[5] = Wr2_ds; wsrc.p[6] = Wl2_sd; wsrc.p[7] = Wr2_sd;
    wsrc.p[8] = Wdec1;                 // rows 0..255  (zd part)
    wsrc.p[9] = Wdec1 + 256 * 256;     // rows 256..511 (zs part)
    transpose_w<<<2560, 256, 0, stream>>>(wsrc, Wt);
    unsigned short* WT[10];
    for (int i = 0; i < 10; ++i) WT[i] = Wt + (size_t)i * 65536;

    // --- CSR build ---
    zero_kernel<<<(NTOT + 255) / 256, 256, 0, stream>>>(cnt, NTOT);
    rank_kernel<<<(NE + 255) / 256, 256, 0, stream>>>(esrc, edst, cnt_drug, cnt_dis,
                                                      rank_sd, rank_ds, NE);
    scan_part<<<SCAN_BLK, 256, 0, stream>>>(cnt, bsum);
    scan_top<<<1, 64, 0, stream>>>(bsum, SCAN_BLK);
    scan_emit<<<SCAN_BLK, 256, 0, stream>>>(cnt, bsum, row_dis, row_drug, inv_dis, inv_drug);
    place_kernel<<<(NE + 255) / 256, 256, 0, stream>>>(esrc, edst, row_drug, row_dis,
                                                       rank_sd, rank_ds, val_sd, val_ds, NE);

    const int AGG_GRID = (NTOT + 3) / 4;
    const int NB_NS = (NS + 127) / 128, NB_ND = (ND + 127) / 128;
    dim3 gemm_grid(NB_NS + NB_ND, 2);

    // --- layer 1 (relu) ---
    agg_bf2<<<AGG_GRID, 256, 0, stream>>>(xd_b, xs_b, row_dis, row_drug, val_ds, val_sd,
                                          inv_dis, inv_drug, aggs, aggd);
    {
        GemmSeg a = { aggs, xs_b, WT[0], WT[1], bl1_ds, zs1, NS, 1, NB_NS };
        GemmSeg b = { aggd, xd_b, WT[2], WT[3], bl1_sd, zd1, ND, 1, NB_ND };
        gemm_bf2<<<gemm_grid, 256, 0, stream>>>(a, b);
    }

    // --- layer 2 (no relu) ---
    agg_bf2<<<AGG_GRID, 256, 0, stream>>>(zd1, zs1, row_dis, row_drug, val_ds, val_sd,
                                          inv_dis, inv_drug, aggs, aggd);
    {
        GemmSeg a = { aggs, zs1, WT[4], WT[5], bl2_ds, zs2, NS, 0, NB_NS };
        GemmSeg b = { aggd, zd1, WT[6], WT[7], bl2_sd, zd2, ND, 0, NB_ND };
        gemm_bf2<<<gemm_grid, 256, 0, stream>>>(a, b);
    }

    // --- decoder projections (fused) ---
    {
        GemmSeg a = { zd2, nullptr, WT[8], nullptr, nullptr, Pd, ND, 0, NB_ND };
        GemmSeg b = { zs2, nullptr, WT[9], nullptr, nullptr, Ps, NS, 0, NB_NS };
        gemm_bf2<<<gemm_grid, 256, 0, stream>>>(a, b);
    }
    dec_edge<<<(EL + 3) / 4, 256, 0, stream>>>(Pd, Ps, lrow, lcol, bdec1, Wdec2, bdec2, outp, EL);
}